// Round 15
// baseline (303.117 us; speedup 1.0000x reference)
//
#include <hip/hip_runtime.h>
#include <hip/hip_bf16.h>

#define NSEQ 256   // N_SEQ (attention axis)
#define NRES 384   // N_RES
#define CM   256   // C_M
#define NH   8
#define HC   32    // head dim

typedef __bf16 bf16x8_t __attribute__((ext_vector_type(8)));
typedef __bf16 bf16x4_t __attribute__((ext_vector_type(4)));
typedef float  f32x4_t  __attribute__((ext_vector_type(4)));
typedef short  s16x4_t  __attribute__((ext_vector_type(4)));
typedef unsigned int u32x2_t __attribute__((ext_vector_type(2)));

static __device__ __forceinline__ f32x4_t mfma16(bf16x8_t a, bf16x8_t b, f32x4_t c) {
    return __builtin_amdgcn_mfma_f32_16x16x32_bf16(a, b, c, 0, 0, 0);
}
// K=16 variant: A,B = 4 bf16 per lane (A[m=l15][k=g4*4+j], B[k=g4*4+j][n=l15])
static __device__ __forceinline__ f32x4_t mfma16k16(s16x4_t a, s16x4_t b, f32x4_t c) {
    return __builtin_amdgcn_mfma_f32_16x16x16bf16_1k(a, b, c, 0, 0, 0);
}

static __device__ __forceinline__ bf16x4_t to_bf4(f32x4_t v) {
    bf16x4_t o;
    o[0] = (__bf16)v[0]; o[1] = (__bf16)v[1];
    o[2] = (__bf16)v[2]; o[3] = (__bf16)v[3];
    return o;
}

static __device__ __forceinline__ unsigned int pkbf(float a, float b) {
    union { __bf16 h[2]; unsigned int u; } t;
    t.h[0] = (__bf16)a; t.h[1] = (__bf16)b;
    return t.u;
}

// ---------------- Kernel 1: weight prep (coalesced LDS-tiled transpose + bf16) ----------------
// wt layout: [5][256 n][256 k], wt[w][n][k] = W[w][k][n].  0=Wq 1=Wk 2=Wv 3=Wg 4=Wo
__global__ __launch_bounds__(256) void wprep_kernel(
        const float* __restrict__ wq, const float* __restrict__ wk,
        const float* __restrict__ wv, const float* __restrict__ wg,
        const float* __restrict__ wo, __bf16* __restrict__ wt) {
    __shared__ float tile[64][65];
    const float* src;
    switch (blockIdx.z) {
        case 0: src = wq; break; case 1: src = wk; break;
        case 2: src = wv; break; case 3: src = wg; break;
        default: src = wo; break;
    }
    __bf16* dst = wt + (size_t)blockIdx.z * (CM * CM);
    int k0 = blockIdx.x * 64;   // rows of W (k)
    int n0 = blockIdx.y * 64;   // cols of W (n)
    int lane = threadIdx.x & 63, wv2 = threadIdx.x >> 6;
    #pragma unroll
    for (int i = 0; i < 16; ++i) {
        int kk = wv2 * 16 + i;
        tile[kk][lane] = src[(size_t)(k0 + kk) * CM + n0 + lane];
    }
    __syncthreads();
    #pragma unroll
    for (int i = 0; i < 16; ++i) {
        int nn = wv2 * 16 + i;
        dst[(size_t)(n0 + nn) * CM + k0 + lane] = (__bf16)tile[lane][nn];
    }
}

// ---------------- Kernel 2: LayerNorm + transpose to (r,s) + bf16 ----------------
// m: (s*NRES + r) rows, fp32.  x: (r*NSEQ + s) rows, bf16.
__global__ __launch_bounds__(256) void ln_kernel(
        const float* __restrict__ m, const float* __restrict__ gamma,
        const float* __restrict__ beta, __bf16* __restrict__ x) {
    int w = threadIdx.x >> 6, lane = threadIdx.x & 63;
    int row = blockIdx.x * 4 + w;                 // row = s*NRES + r
    const float4 mv = *reinterpret_cast<const float4*>(m + (size_t)row * CM + lane * 4);
    float s1 = mv.x + mv.y + mv.z + mv.w;
    float s2 = mv.x * mv.x + mv.y * mv.y + mv.z * mv.z + mv.w * mv.w;
    #pragma unroll
    for (int d = 1; d < 64; d <<= 1) {
        s1 += __shfl_xor(s1, d);
        s2 += __shfl_xor(s2, d);
    }
    float mu  = s1 * (1.0f / CM);
    float var = s2 * (1.0f / CM) - mu * mu;
    float rs  = rsqrtf(var + 1e-5f);
    const float4 gv = *reinterpret_cast<const float4*>(gamma + lane * 4);
    const float4 bv = *reinterpret_cast<const float4*>(beta + lane * 4);
    int s = row / NRES;
    int r = row - s * NRES;
    int drow = r * NSEQ + s;
    bf16x4_t o;
    o[0] = (__bf16)((mv.x - mu) * rs * gv.x + bv.x);
    o[1] = (__bf16)((mv.y - mu) * rs * gv.y + bv.y);
    o[2] = (__bf16)((mv.z - mu) * rs * gv.z + bv.z);
    o[3] = (__bf16)((mv.w - mu) * rs * gv.w + bv.w);
    *reinterpret_cast<bf16x4_t*>(x + (size_t)drow * CM + lane * 4) = o;
}

// ---------------- Kernel 3: fused QKVG-projection + attention + gating ----------------
// R12 structure (K16 register-PV, no p_s LDS transit, single barrier).
// R14: softmax without max subtraction (validated R7: logits ~N(0,1) after
// scale, exp2 args bounded ~|6|, mathematically identical) -- removes the
// cross-lane max round-trip from each qt's critical path.
__global__ __launch_bounds__(256, 2) void attn_kernel(
        const __bf16* __restrict__ x, const __bf16* __restrict__ wt,
        const float* __restrict__ bg, __bf16* __restrict__ go) {
    const int KRW = 40;   // k_s/q_s row stride (elems)
    const int VRW = 264;  // v_sT row stride (elems)

    __shared__ __align__(16) char smem[57856];
    __bf16* k_s  = reinterpret_cast<__bf16*>(smem);           // [256][40]  20480B
    __bf16* q_s  = reinterpret_cast<__bf16*>(smem + 20480);   // [256][40]  20480B
    __bf16* v_sT = reinterpret_cast<__bf16*>(smem + 40960);   // [32][264]  16896B

    int tid = threadIdx.x;
    int w = tid >> 6, lane = tid & 63;
    int l15 = lane & 15, g4 = lane >> 4;

    // XCD swizzle: dispatch XCD = bid % 8; the 8 h-blocks of one r stay on one XCD.
    int bid = blockIdx.x;
    int nid = (bid & 7) * 384 + (bid >> 3);
    int r = nid >> 3, h = nid & 7;

    const __bf16* xr = x + (size_t)r * NSEQ * CM;

    // ---- Phase A: q,k,v,g tiles (256 x 32 each); each x fragment loaded once ----
    const f32x4_t zf = {0.0f, 0.0f, 0.0f, 0.0f};
    f32x4_t acc[4][4][2];                     // [wi][mt][ct], wi: 0=q 1=k 2=v 3=g
    #pragma unroll
    for (int wi = 0; wi < 4; ++wi)
        #pragma unroll
        for (int mt = 0; mt < 4; ++mt)
            #pragma unroll
            for (int ct = 0; ct < 2; ++ct) acc[wi][mt][ct] = zf;

    #pragma unroll
    for (int kb = 0; kb < 8; ++kb) {
        bf16x8_t a[4];
        #pragma unroll
        for (int mt = 0; mt < 4; ++mt)
            a[mt] = *reinterpret_cast<const bf16x8_t*>(
                xr + (w * 64 + mt * 16 + l15) * CM + kb * 32 + g4 * 8);
        #pragma unroll
        for (int wi = 0; wi < 4; ++wi) {
            const __bf16* wslice = wt + (size_t)wi * (CM * CM) + (h * HC) * CM;
            bf16x8_t b[2];
            #pragma unroll
            for (int ct = 0; ct < 2; ++ct)
                b[ct] = *reinterpret_cast<const bf16x8_t*>(
                    wslice + (ct * 16 + l15) * CM + kb * 32 + g4 * 8);
            #pragma unroll
            for (int mt = 0; mt < 4; ++mt)
                #pragma unroll
                for (int ct = 0; ct < 2; ++ct)
                    acc[wi][mt][ct] = mfma16(a[mt], b[ct], acc[wi][mt][ct]);
        }
    }

    // scatter q,k to LDS (scalar bf16), v transposed (b64), g stays in regs
    #pragma unroll
    for (int mt = 0; mt < 4; ++mt)
        #pragma unroll
        for (int ct = 0; ct < 2; ++ct) {
            #pragma unroll
            for (int i = 0; i < 4; ++i) {
                q_s[(w * 64 + mt * 16 + g4 * 4 + i) * KRW + ct * 16 + l15] =
                    (__bf16)acc[0][mt][ct][i];
                k_s[(w * 64 + mt * 16 + g4 * 4 + i) * KRW + ct * 16 + l15] =
                    (__bf16)acc[1][mt][ct][i];
            }
            *reinterpret_cast<bf16x4_t*>(
                v_sT + (ct * 16 + l15) * VRW + w * 64 + mt * 16 + g4 * 4) =
                to_bf4(acc[2][mt][ct]);
        }
    __syncthreads();

    // ---- hoist K (all 256 keys) and Q (own 64 rows) fragments into registers ----
    bf16x8_t kf[16];
    #pragma unroll
    for (int kt = 0; kt < 16; ++kt)
        kf[kt] = *reinterpret_cast<const bf16x8_t*>(k_s + (kt * 16 + l15) * KRW + g4 * 8);
    bf16x8_t qf[4];
    #pragma unroll
    for (int qt = 0; qt < 4; ++qt)
        qf[qt] = *reinterpret_cast<const bf16x8_t*>(q_s + (w * 64 + qt * 16 + l15) * KRW + g4 * 8);
    // no second barrier needed: nothing writes LDS after this point

    float bgv[2];
    bgv[0] = bg[h * HC + l15];
    bgv[1] = bg[h * HC + 16 + l15];
    const float cs = 0.17677669529663687f * 1.4426950408889634f;  // 1/sqrt(32) * log2e
    const float l2e = 1.4426950408889634f;

    __bf16* gor = go + (((size_t)r * NH + h) * NSEQ) * HC;

    #pragma unroll
    for (int qt = 0; qt < 4; ++qt) {
        // S^T = mfma(K, Q): lane holds q = w*64+qt*16+l15 (fixed), keys kt*16+g4*4+i
        f32x4_t sacc[16];
        #pragma unroll
        for (int kt = 0; kt < 16; ++kt) sacc[kt] = zf;
        __builtin_amdgcn_s_setprio(1);
        #pragma unroll
        for (int kt = 0; kt < 16; ++kt) sacc[kt] = mfma16(kf[kt], qf[qt], sacc[kt]);
        __builtin_amdgcn_s_setprio(0);

        // softmax without max subtraction (logits bounded ~|4|; exact in f32;
        // validated R7). exp starts immediately off sacc; 4 parallel partials.
        f32x4_t s4v = zf;
        #pragma unroll
        for (int kt = 0; kt < 16; ++kt)
            #pragma unroll
            for (int i = 0; i < 4; ++i) {
                float e = exp2f(sacc[kt][i] * cs);
                sacc[kt][i] = e;
                s4v[i] += e;
            }
        float sum = (s4v[0] + s4v[1]) + (s4v[2] + s4v[3]);
        sum += __shfl_xor(sum, 16);
        sum += __shfl_xor(sum, 32);
        float inv = 1.0f / sum;

        // PV directly from registers: P fragment (A of 16x16x16) == sacc layout.
        // Per kt: pack 4 normalized bf16, read B = v_sT[c][kt*16+g4*4..+3], MFMA.
        f32x4_t oacc[2];
        oacc[0] = zf; oacc[1] = zf;
        __builtin_amdgcn_s_setprio(1);
        #pragma unroll
        for (int kt = 0; kt < 16; ++kt) {
            u32x2_t pw;
            pw[0] = pkbf(sacc[kt][0] * inv, sacc[kt][1] * inv);
            pw[1] = pkbf(sacc[kt][2] * inv, sacc[kt][3] * inv);
            s16x4_t pa = __builtin_bit_cast(s16x4_t, pw);
            #pragma unroll
            for (int ct = 0; ct < 2; ++ct) {
                s16x4_t vb = *reinterpret_cast<const s16x4_t*>(
                    v_sT + (ct * 16 + l15) * VRW + kt * 16 + g4 * 4);
                oacc[ct] = mfma16k16(pa, vb, oacc[ct]);
            }
        }
        __builtin_amdgcn_s_setprio(0);

        // gated epilogue: g accumulator layout == o accumulator layout (mt=qt)
        #pragma unroll
        for (int ct = 0; ct < 2; ++ct)
            #pragma unroll
            for (int i = 0; i < 4; ++i) {
                float t  = acc[3][qt][ct][i] + bgv[ct];
                float gs = 1.0f / (1.0f + exp2f(-t * l2e));
                int srow = w * 64 + qt * 16 + g4 * 4 + i;
                gor[(size_t)srow * HC + ct * 16 + l15] = (__bf16)(gs * oacc[ct][i]);
            }
    }
}

// ---------------- Kernel 4: out = (g*o) @ Wo + bo, scatter rows to (s,r) order ----------------
// go layout: [r][h][s][c]; k index kb*32+g4*8 maps to h=kb, c offset g4*8.
// XCD-swizzled so the consumer of go[r] runs on the XCD that produced it.
__global__ __launch_bounds__(256, 2) void outgemm_kernel(
        const __bf16* __restrict__ go, const __bf16* __restrict__ wto,
        const float* __restrict__ bo, float* __restrict__ out) {
    int tid = threadIdx.x, w = tid >> 6, lane = tid & 63;
    int l15 = lane & 15, g4 = lane >> 4;
    int b = blockIdx.x;
    int u = (b & 7) * 192 + (b >> 3);    // bijective, 1536 % 8 == 0
    int j0 = u * 64 + w * 16;            // j = r*NSEQ + s; r uniform per block
    int rb = j0 >> 8;
    int s0 = j0 & (NSEQ - 1);
    const __bf16* gor = go + ((size_t)rb * NH) * NSEQ * HC;
    const f32x4_t zf = {0.0f, 0.0f, 0.0f, 0.0f};
    f32x4_t acc[16];
    #pragma unroll
    for (int nt = 0; nt < 16; ++nt) acc[nt] = zf;
    #pragma unroll
    for (int kb = 0; kb < 8; ++kb) {
        bf16x8_t a = *reinterpret_cast<const bf16x8_t*>(
            gor + ((size_t)kb * NSEQ + s0 + l15) * HC + g4 * 8);
        #pragma unroll
        for (int nt = 0; nt < 16; ++nt) {
            bf16x8_t b2 = *reinterpret_cast<const bf16x8_t*>(
                wto + (nt * 16 + l15) * CM + kb * 32 + g4 * 8);
            acc[nt] = mfma16(a, b2, acc[nt]);
        }
    }
    #pragma unroll
    for (int nt = 0; nt < 16; ++nt) {
        float bias = bo[nt * 16 + l15];
        #pragma unroll
        for (int i = 0; i < 4; ++i) {
            int s = s0 + g4 * 4 + i;
            out[((size_t)(s * NRES + rb)) * CM + nt * 16 + l15] = acc[nt][i] + bias;
        }
    }
}

extern "C" void kernel_launch(void* const* d_in, const int* in_sizes, int n_in,
                              void* d_out, int out_size, void* d_ws, size_t ws_size,
                              hipStream_t stream) {
    const float* m     = (const float*)d_in[0];
    const float* gamma = (const float*)d_in[1];
    const float* beta  = (const float*)d_in[2];
    const float* wq    = (const float*)d_in[3];
    const float* wk    = (const float*)d_in[4];
    const float* wv    = (const float*)d_in[5];
    const float* wg    = (const float*)d_in[6];
    const float* bg    = (const float*)d_in[7];
    const float* wo    = (const float*)d_in[8];
    const float* bo    = (const float*)d_in[9];

    char* ws = (char*)d_ws;
    const size_t X_OFF  = 1u << 20;
    const size_t GO_OFF = X_OFF + (size_t)NRES * NSEQ * CM * 2;
    const size_t NEED   = GO_OFF + (size_t)NRES * NSEQ * CM * 2;
    if (ws_size < NEED) return;

    __bf16* wt = (__bf16*)ws;
    __bf16* x  = (__bf16*)(ws + X_OFF);
    __bf16* go = (__bf16*)(ws + GO_OFF);

    wprep_kernel<<<dim3(4, 4, 5), 256, 0, stream>>>(wq, wk, wv, wg, wo, wt);
    ln_kernel<<<(NSEQ * NRES) / 4, 256, 0, stream>>>(m, gamma, beta, x);
    attn_kernel<<<NRES * NH, 256, 0, stream>>>(x, wt, bg, go);
    outgemm_kernel<<<(NRES * NSEQ) / 64, 256, 0, stream>>>(go, wt + 4 * (CM * CM), bo, (float*)d_out);
}

// Round 16
// 300.100 us; speedup vs baseline: 1.0101x; 1.0101x over previous
//
#include <hip/hip_runtime.h>
#include <hip/hip_bf16.h>

#define NSEQ 256   // N_SEQ (attention axis)
#define NRES 384   // N_RES
#define CM   256   // C_M
#define NH   8
#define HC   32    // head dim

typedef __bf16 bf16x8_t __attribute__((ext_vector_type(8)));
typedef __bf16 bf16x4_t __attribute__((ext_vector_type(4)));
typedef float  f32x4_t  __attribute__((ext_vector_type(4)));
typedef short  s16x4_t  __attribute__((ext_vector_type(4)));
typedef unsigned int u32x2_t __attribute__((ext_vector_type(2)));

static __device__ __forceinline__ f32x4_t mfma16(bf16x8_t a, bf16x8_t b, f32x4_t c) {
    return __builtin_amdgcn_mfma_f32_16x16x32_bf16(a, b, c, 0, 0, 0);
}
// K=16 variant: A,B = 4 bf16 per lane (A[m=l15][k=g4*4+j], B[k=g4*4+j][n=l15])
static __device__ __forceinline__ f32x4_t mfma16k16(s16x4_t a, s16x4_t b, f32x4_t c) {
    return __builtin_amdgcn_mfma_f32_16x16x16bf16_1k(a, b, c, 0, 0, 0);
}

static __device__ __forceinline__ bf16x4_t to_bf4(f32x4_t v) {
    bf16x4_t o;
    o[0] = (__bf16)v[0]; o[1] = (__bf16)v[1];
    o[2] = (__bf16)v[2]; o[3] = (__bf16)v[3];
    return o;
}

static __device__ __forceinline__ unsigned int pkbf(float a, float b) {
    union { __bf16 h[2]; unsigned int u; } t;
    t.h[0] = (__bf16)a; t.h[1] = (__bf16)b;
    return t.u;
}

// ---------------- Kernel 1: weight prep (coalesced LDS-tiled transpose + bf16) ----------------
// wt layout: [5][256 n][256 k], wt[w][n][k] = W[w][k][n].  0=Wq 1=Wk 2=Wv 3=Wg 4=Wo
__global__ __launch_bounds__(256) void wprep_kernel(
        const float* __restrict__ wq, const float* __restrict__ wk,
        const float* __restrict__ wv, const float* __restrict__ wg,
        const float* __restrict__ wo, __bf16* __restrict__ wt) {
    __shared__ float tile[64][65];
    const float* src;
    switch (blockIdx.z) {
        case 0: src = wq; break; case 1: src = wk; break;
        case 2: src = wv; break; case 3: src = wg; break;
        default: src = wo; break;
    }
    __bf16* dst = wt + (size_t)blockIdx.z * (CM * CM);
    int k0 = blockIdx.x * 64;   // rows of W (k)
    int n0 = blockIdx.y * 64;   // cols of W (n)
    int lane = threadIdx.x & 63, wv2 = threadIdx.x >> 6;
    #pragma unroll
    for (int i = 0; i < 16; ++i) {
        int kk = wv2 * 16 + i;
        tile[kk][lane] = src[(size_t)(k0 + kk) * CM + n0 + lane];
    }
    __syncthreads();
    #pragma unroll
    for (int i = 0; i < 16; ++i) {
        int nn = wv2 * 16 + i;
        dst[(size_t)(n0 + nn) * CM + k0 + lane] = (__bf16)tile[lane][nn];
    }
}

// ---------------- Kernel 2: LayerNorm + transpose to (r,s) + bf16 ----------------
// m: (s*NRES + r) rows, fp32.  x: (r*NSEQ + s) rows, bf16.
__global__ __launch_bounds__(256) void ln_kernel(
        const float* __restrict__ m, const float* __restrict__ gamma,
        const float* __restrict__ beta, __bf16* __restrict__ x) {
    int w = threadIdx.x >> 6, lane = threadIdx.x & 63;
    int row = blockIdx.x * 4 + w;                 // row = s*NRES + r
    const float4 mv = *reinterpret_cast<const float4*>(m + (size_t)row * CM + lane * 4);
    float s1 = mv.x + mv.y + mv.z + mv.w;
    float s2 = mv.x * mv.x + mv.y * mv.y + mv.z * mv.z + mv.w * mv.w;
    #pragma unroll
    for (int d = 1; d < 64; d <<= 1) {
        s1 += __shfl_xor(s1, d);
        s2 += __shfl_xor(s2, d);
    }
    float mu  = s1 * (1.0f / CM);
    float var = s2 * (1.0f / CM) - mu * mu;
    float rs  = rsqrtf(var + 1e-5f);
    const float4 gv = *reinterpret_cast<const float4*>(gamma + lane * 4);
    const float4 bv = *reinterpret_cast<const float4*>(beta + lane * 4);
    int s = row / NRES;
    int r = row - s * NRES;
    int drow = r * NSEQ + s;
    bf16x4_t o;
    o[0] = (__bf16)((mv.x - mu) * rs * gv.x + bv.x);
    o[1] = (__bf16)((mv.y - mu) * rs * gv.y + bv.y);
    o[2] = (__bf16)((mv.z - mu) * rs * gv.z + bv.z);
    o[3] = (__bf16)((mv.w - mu) * rs * gv.w + bv.w);
    *reinterpret_cast<bf16x4_t*>(x + (size_t)drow * CM + lane * 4) = o;
}

// ---------------- Kernel 3: fused QKVG-projection + attention + gating ----------------
// Best-measured configuration (R12): R6 base structure + K16 register-PV.
// One block per (r,h), 4 waves; wave w owns seq rows [w*64, w*64+64).
// kb-outer Phase A (x read once from L2), kf[16]+qf[4] hoist, exact softmax,
// PV consumes P straight from registers via K=16 MFMA (A-fragment == swapped-QK
// sacc layout) -- no p_s LDS round-trip, single barrier. go [r][h][s][c].
__global__ __launch_bounds__(256, 2) void attn_kernel(
        const __bf16* __restrict__ x, const __bf16* __restrict__ wt,
        const float* __restrict__ bg, __bf16* __restrict__ go) {
    const int KRW = 40;   // k_s/q_s row stride (elems)
    const int VRW = 264;  // v_sT row stride (elems)

    __shared__ __align__(16) char smem[57856];
    __bf16* k_s  = reinterpret_cast<__bf16*>(smem);           // [256][40]  20480B
    __bf16* q_s  = reinterpret_cast<__bf16*>(smem + 20480);   // [256][40]  20480B
    __bf16* v_sT = reinterpret_cast<__bf16*>(smem + 40960);   // [32][264]  16896B

    int tid = threadIdx.x;
    int w = tid >> 6, lane = tid & 63;
    int l15 = lane & 15, g4 = lane >> 4;

    // XCD swizzle: dispatch XCD = bid % 8; the 8 h-blocks of one r stay on one XCD.
    int bid = blockIdx.x;
    int nid = (bid & 7) * 384 + (bid >> 3);
    int r = nid >> 3, h = nid & 7;

    const __bf16* xr = x + (size_t)r * NSEQ * CM;

    // ---- Phase A: q,k,v,g tiles (256 x 32 each); each x fragment loaded once ----
    const f32x4_t zf = {0.0f, 0.0f, 0.0f, 0.0f};
    f32x4_t acc[4][4][2];                     // [wi][mt][ct], wi: 0=q 1=k 2=v 3=g
    #pragma unroll
    for (int wi = 0; wi < 4; ++wi)
        #pragma unroll
        for (int mt = 0; mt < 4; ++mt)
            #pragma unroll
            for (int ct = 0; ct < 2; ++ct) acc[wi][mt][ct] = zf;

    #pragma unroll
    for (int kb = 0; kb < 8; ++kb) {
        bf16x8_t a[4];
        #pragma unroll
        for (int mt = 0; mt < 4; ++mt)
            a[mt] = *reinterpret_cast<const bf16x8_t*>(
                xr + (w * 64 + mt * 16 + l15) * CM + kb * 32 + g4 * 8);
        #pragma unroll
        for (int wi = 0; wi < 4; ++wi) {
            const __bf16* wslice = wt + (size_t)wi * (CM * CM) + (h * HC) * CM;
            bf16x8_t b[2];
            #pragma unroll
            for (int ct = 0; ct < 2; ++ct)
                b[ct] = *reinterpret_cast<const bf16x8_t*>(
                    wslice + (ct * 16 + l15) * CM + kb * 32 + g4 * 8);
            #pragma unroll
            for (int mt = 0; mt < 4; ++mt)
                #pragma unroll
                for (int ct = 0; ct < 2; ++ct)
                    acc[wi][mt][ct] = mfma16(a[mt], b[ct], acc[wi][mt][ct]);
        }
    }

    // scatter q,k to LDS (scalar bf16), v transposed (b64), g stays in regs
    #pragma unroll
    for (int mt = 0; mt < 4; ++mt)
        #pragma unroll
        for (int ct = 0; ct < 2; ++ct) {
            #pragma unroll
            for (int i = 0; i < 4; ++i) {
                q_s[(w * 64 + mt * 16 + g4 * 4 + i) * KRW + ct * 16 + l15] =
                    (__bf16)acc[0][mt][ct][i];
                k_s[(w * 64 + mt * 16 + g4 * 4 + i) * KRW + ct * 16 + l15] =
                    (__bf16)acc[1][mt][ct][i];
            }
            *reinterpret_cast<bf16x4_t*>(
                v_sT + (ct * 16 + l15) * VRW + w * 64 + mt * 16 + g4 * 4) =
                to_bf4(acc[2][mt][ct]);
        }
    __syncthreads();

    // ---- hoist K (all 256 keys) and Q (own 64 rows) fragments into registers ----
    bf16x8_t kf[16];
    #pragma unroll
    for (int kt = 0; kt < 16; ++kt)
        kf[kt] = *reinterpret_cast<const bf16x8_t*>(k_s + (kt * 16 + l15) * KRW + g4 * 8);
    bf16x8_t qf[4];
    #pragma unroll
    for (int qt = 0; qt < 4; ++qt)
        qf[qt] = *reinterpret_cast<const bf16x8_t*>(q_s + (w * 64 + qt * 16 + l15) * KRW + g4 * 8);
    // no second barrier needed: nothing writes LDS after this point

    float bgv[2];
    bgv[0] = bg[h * HC + l15];
    bgv[1] = bg[h * HC + 16 + l15];
    const float cs = 0.17677669529663687f * 1.4426950408889634f;  // 1/sqrt(32) * log2e
    const float l2e = 1.4426950408889634f;

    __bf16* gor = go + (((size_t)r * NH + h) * NSEQ) * HC;

    #pragma unroll
    for (int qt = 0; qt < 4; ++qt) {
        // S^T = mfma(K, Q): lane holds q = w*64+qt*16+l15 (fixed), keys kt*16+g4*4+i
        f32x4_t sacc[16];
        #pragma unroll
        for (int kt = 0; kt < 16; ++kt) sacc[kt] = zf;
        __builtin_amdgcn_s_setprio(1);
        #pragma unroll
        for (int kt = 0; kt < 16; ++kt) sacc[kt] = mfma16(kf[kt], qf[qt], sacc[kt]);
        __builtin_amdgcn_s_setprio(0);

        // exact softmax over keys: 64 local values + xor16/xor32 reduce
        float mx = -1e30f;
        #pragma unroll
        for (int kt = 0; kt < 16; ++kt)
            #pragma unroll
            for (int i = 0; i < 4; ++i) mx = fmaxf(mx, sacc[kt][i]);
        mx = fmaxf(mx, __shfl_xor(mx, 16));
        mx = fmaxf(mx, __shfl_xor(mx, 32));
        float nmc = -mx * cs;
        float sum = 0.0f;
        #pragma unroll
        for (int kt = 0; kt < 16; ++kt)
            #pragma unroll
            for (int i = 0; i < 4; ++i) {
                float e = exp2f(__builtin_fmaf(sacc[kt][i], cs, nmc));
                sacc[kt][i] = e;
                sum += e;
            }
        sum += __shfl_xor(sum, 16);
        sum += __shfl_xor(sum, 32);
        float inv = 1.0f / sum;

        // PV directly from registers: P fragment (A of 16x16x16) == sacc layout.
        // Per kt: pack 4 normalized bf16, read B = v_sT[c][kt*16+g4*4..+3], MFMA.
        f32x4_t oacc[2];
        oacc[0] = zf; oacc[1] = zf;
        __builtin_amdgcn_s_setprio(1);
        #pragma unroll
        for (int kt = 0; kt < 16; ++kt) {
            u32x2_t pw;
            pw[0] = pkbf(sacc[kt][0] * inv, sacc[kt][1] * inv);
            pw[1] = pkbf(sacc[kt][2] * inv, sacc[kt][3] * inv);
            s16x4_t pa = __builtin_bit_cast(s16x4_t, pw);
            #pragma unroll
            for (int ct = 0; ct < 2; ++ct) {
                s16x4_t vb = *reinterpret_cast<const s16x4_t*>(
                    v_sT + (ct * 16 + l15) * VRW + kt * 16 + g4 * 4);
                oacc[ct] = mfma16k16(pa, vb, oacc[ct]);
            }
        }
        __builtin_amdgcn_s_setprio(0);

        // gated epilogue: g accumulator layout == o accumulator layout (mt=qt)
        #pragma unroll
        for (int ct = 0; ct < 2; ++ct)
            #pragma unroll
            for (int i = 0; i < 4; ++i) {
                float t  = acc[3][qt][ct][i] + bgv[ct];
                float gs = 1.0f / (1.0f + exp2f(-t * l2e));
                int srow = w * 64 + qt * 16 + g4 * 4 + i;
                gor[(size_t)srow * HC + ct * 16 + l15] = (__bf16)(gs * oacc[ct][i]);
            }
    }
}

// ---------------- Kernel 4: out = (g*o) @ Wo + bo, scatter rows to (s,r) order ----------------
// go layout: [r][h][s][c]; k index kb*32+g4*8 maps to h=kb, c offset g4*8.
// XCD-swizzled so the consumer of go[r] runs on the XCD that produced it.
__global__ __launch_bounds__(256, 2) void outgemm_kernel(
        const __bf16* __restrict__ go, const __bf16* __restrict__ wto,
        const float* __restrict__ bo, float* __restrict__ out) {
    int tid = threadIdx.x, w = tid >> 6, lane = tid & 63;
    int l15 = lane & 15, g4 = lane >> 4;
    int b = blockIdx.x;
    int u = (b & 7) * 192 + (b >> 3);    // bijective, 1536 % 8 == 0
    int j0 = u * 64 + w * 16;            // j = r*NSEQ + s; r uniform per block
    int rb = j0 >> 8;
    int s0 = j0 & (NSEQ - 1);
    const __bf16* gor = go + ((size_t)rb * NH) * NSEQ * HC;
    const f32x4_t zf = {0.0f, 0.0f, 0.0f, 0.0f};
    f32x4_t acc[16];
    #pragma unroll
    for (int nt = 0; nt < 16; ++nt) acc[nt] = zf;
    #pragma unroll
    for (int kb = 0; kb < 8; ++kb) {
        bf16x8_t a = *reinterpret_cast<const bf16x8_t*>(
            gor + ((size_t)kb * NSEQ + s0 + l15) * HC + g4 * 8);
        #pragma unroll
        for (int nt = 0; nt < 16; ++nt) {
            bf16x8_t b2 = *reinterpret_cast<const bf16x8_t*>(
                wto + (nt * 16 + l15) * CM + kb * 32 + g4 * 8);
            acc[nt] = mfma16(a, b2, acc[nt]);
        }
    }
    #pragma unroll
    for (int nt = 0; nt < 16; ++nt) {
        float bias = bo[nt * 16 + l15];
        #pragma unroll
        for (int i = 0; i < 4; ++i) {
            int s = s0 + g4 * 4 + i;
            out[((size_t)(s * NRES + rb)) * CM + nt * 16 + l15] = acc[nt][i] + bias;
        }
    }
}

extern "C" void kernel_launch(void* const* d_in, const int* in_sizes, int n_in,
                              void* d_out, int out_size, void* d_ws, size_t ws_size,
                              hipStream_t stream) {
    const float* m     = (const float*)d_in[0];
    const float* gamma = (const float*)d_in[1];
    const float* beta  = (const float*)d_in[2];
    const float* wq    = (const float*)d_in[3];
    const float* wk    = (const float*)d_in[4];
    const float* wv    = (const float*)d_in[5];
    const float* wg    = (const float*)d_in[6];
    const float* bg    = (const float*)d_in[7];
    const float* wo    = (const float*)d_in[8];
    const float* bo    = (const float*)d_in[9];

    char* ws = (char*)d_ws;
    const size_t X_OFF  = 1u << 20;
    const size_t GO_OFF = X_OFF + (size_t)NRES * NSEQ * CM * 2;
    const size_t NEED   = GO_OFF + (size_t)NRES * NSEQ * CM * 2;
    if (ws_size < NEED) return;

    __bf16* wt = (__bf16*)ws;
    __bf16* x  = (__bf16*)(ws + X_OFF);
    __bf16* go = (__bf16*)(ws + GO_OFF);

    wprep_kernel<<<dim3(4, 4, 5), 256, 0, stream>>>(wq, wk, wv, wg, wo, wt);
    ln_kernel<<<(NSEQ * NRES) / 4, 256, 0, stream>>>(m, gamma, beta, x);
    attn_kernel<<<NRES * NH, 256, 0, stream>>>(x, wt, bg, go);
    outgemm_kernel<<<(NRES * NSEQ) / 64, 256, 0, stream>>>(go, wt + 4 * (CM * CM), bo, (float*)d_out);
}